// Round 5
// baseline (2003.874 us; speedup 1.0000x reference)
//
#include <hip/hip_runtime.h>

#define NG 16     // num_graphs (fixed by problem)
#define D 64      // feature width at every aggregation point
#define SLOT 64   // CSR slots per node; in-degree <= ~Poisson(8.5), P(>=64) negligible

// ---------------------------------------------------------------------------
// Build fixed-stride CSR by destination. One int atomic per VALID edge.
// ---------------------------------------------------------------------------
__global__ void build_csr_kernel(const int* __restrict__ ei,
                                 int* __restrict__ fill,
                                 int* __restrict__ col,
                                 int E, int per, int tmul) {
  int e = blockIdx.x * blockDim.x + threadIdx.x;
  if (e >= E) return;
  int src = ei[e];
  int dst = ei[E + e];
  int g = e / per;            // compiler magic-div
  int thr = g * tmul;
  if (src >= thr && dst >= thr) {
    int k = atomicAdd(&fill[dst], 1);
    if (k < SLOT) col[dst * SLOT + k] = src;   // clamp is paranoia-only
  }
}

// ---------------------------------------------------------------------------
// Fused layer: gather + (optional BN fold) + 2-linear MLP (+ optional BN-stats
// epilogue). Block = 512 threads, 64 nodes.
//  Phase A: 16 lanes/node, float4 gathers -> s_in.
//  Phase B: thread (q,r2) computes nodes {2r2,2r2+1} x its cols. Stage-1
//           results stay in registers; stage 2 broadcasts them via 16-lane
//           __shfl (no s_mid). Wb read from global (L1-resident, coalesced).
//  LDS = s_in + Wa only -> 4 blocks/CU (100% wave occupancy).
// ---------------------------------------------------------------------------
template <int MID, bool FOLD_BN, bool EMIT_STATS>
__global__ __launch_bounds__(512, 8) void fused_layer_kernel(
    const float* __restrict__ feat, const int* __restrict__ col,
    const int* __restrict__ deg,
    const float* __restrict__ bn_sum, const float* __restrict__ bn_sq,
    const float* __restrict__ bn_gamma, const float* __restrict__ bn_beta,
    float invN,
    const float* __restrict__ Wa, const float* __restrict__ ba,
    const float* __restrict__ Wb, const float* __restrict__ bb,
    float* __restrict__ out,
    float* __restrict__ st_sum, float* __restrict__ st_sq, int N) {
  constexpr int NPB = 64;        // nodes per block
  constexpr int INP = D + 4;     // padded row stride (272B = 17 float4s, conflict-free)
  __shared__ float s_in[NPB * INP];
  __shared__ float s_Wa[D * MID];
  __shared__ float s_bna[FOLD_BN ? D : 1];
  __shared__ float s_bnb[FOLD_BN ? D : 1];

  int tid = threadIdx.x;

  // Stage Wa (coalesced float4, once per block).
  {
    const float4* wa4 = (const float4*)Wa;
    float4* sa4 = (float4*)s_Wa;
    constexpr int NW = D * MID / 4;
#pragma unroll
    for (int i = tid; i < NW; i += 512) sa4[i] = wa4[i];
  }
  if (FOLD_BN && tid < D) {
    float mean = bn_sum[tid] * invN;
    float var = bn_sq[tid] * invN - mean * mean;
    float av = bn_gamma[tid] * rsqrtf(var + 1e-5f);
    s_bna[tid] = av;
    s_bnb[tid] = bn_beta[tid] - mean * av;
  }
  __syncthreads();

  int q = tid & 15;               // lane within 16-group
  int base = blockIdx.x * NPB;

  // ---- Phase A: gather + self + optional BN fold -> LDS rows ----
  {
    int ns = tid >> 4;            // 0..31
#pragma unroll
    for (int pass = 0; pass < 2; pass++) {
      int slot = ns + 32 * pass;
      int node = base + slot;
      if (node < N) {
        int d = min(deg[node], SLOT);
        const int* cl = col + node * SLOT;
        float4 acc = *(const float4*)(feat + (size_t)node * D + q * 4);  // self
        int j = 0;
        for (; j + 4 <= d; j += 4) {
          int4 s4 = *(const int4*)(cl + j);
          float4 v0 = *(const float4*)(feat + (size_t)s4.x * D + q * 4);
          float4 v1 = *(const float4*)(feat + (size_t)s4.y * D + q * 4);
          float4 v2 = *(const float4*)(feat + (size_t)s4.z * D + q * 4);
          float4 v3 = *(const float4*)(feat + (size_t)s4.w * D + q * 4);
          acc.x += v0.x + v1.x + v2.x + v3.x;
          acc.y += v0.y + v1.y + v2.y + v3.y;
          acc.z += v0.z + v1.z + v2.z + v3.z;
          acc.w += v0.w + v1.w + v2.w + v3.w;
        }
        for (; j < d; j++) {
          int s = cl[j];
          float4 v = *(const float4*)(feat + (size_t)s * D + q * 4);
          acc.x += v.x; acc.y += v.y; acc.z += v.z; acc.w += v.w;
        }
        if (FOLD_BN) {
          float dp = (float)(d + 1);
          int c = q * 4;
          acc.x = s_bna[c + 0] * acc.x + dp * s_bnb[c + 0];
          acc.y = s_bna[c + 1] * acc.y + dp * s_bnb[c + 1];
          acc.z = s_bna[c + 2] * acc.z + dp * s_bnb[c + 2];
          acc.w = s_bna[c + 3] * acc.w + dp * s_bnb[c + 3];
        }
        *(float4*)&s_in[slot * INP + q * 4] = acc;
      }
    }
  }
  __syncthreads();

  // ---- Phase B: register-tiled MLP, s_mid replaced by 16-lane shuffles ----
  int r2 = tid >> 4;              // 0..31 -> nodes 2r2, 2r2+1
  int n0 = 2 * r2, n1 = n0 + 1;
  constexpr int C1 = MID / 16;    // stage-1 cols per thread (2 or 4)
  float4 o0, o1;
  {
    // stage 1: mid = relu(in @ Wa + ba), kept in registers
    float acc0[C1], acc1[C1];
#pragma unroll
    for (int u = 0; u < C1; u++) { acc0[u] = ba[q * C1 + u]; acc1[u] = acc0[u]; }
#pragma unroll 4
    for (int j = 0; j < D; j++) {
      float v0 = s_in[n0 * INP + j];
      float v1 = s_in[n1 * INP + j];
#pragma unroll
      for (int u = 0; u < C1; u++) {
        float w = s_Wa[j * MID + q * C1 + u];   // b64/b128, group-broadcast
        acc0[u] += v0 * w;
        acc1[u] += v1 * w;
      }
    }
#pragma unroll
    for (int u = 0; u < C1; u++) {
      acc0[u] = fmaxf(acc0[u], 0.f);
      acc1[u] = fmaxf(acc1[u], 0.f);
    }

    // stage 2: out cols 4q..4q+3; mid[k] owner lane = k/C1, reg = k%C1
    const float4* wb4 = (const float4*)Wb;
    o0 = *(const float4*)(bb + q * 4);
    o1 = o0;
#pragma unroll
    for (int k = 0; k < MID; k++) {
      float m0 = __shfl(acc0[k % C1], k / C1, 16);
      float m1 = __shfl(acc1[k % C1], k / C1, 16);
      float4 w = wb4[k * 16 + q];               // global: coalesced, L1-hot
      o0.x += m0 * w.x; o0.y += m0 * w.y; o0.z += m0 * w.z; o0.w += m0 * w.w;
      o1.x += m1 * w.x; o1.y += m1 * w.y; o1.z += m1 * w.z; o1.w += m1 * w.w;
    }
    int node0 = base + n0, node1 = base + n1;
    o0.x = fmaxf(o0.x, 0.f); o0.y = fmaxf(o0.y, 0.f);
    o0.z = fmaxf(o0.z, 0.f); o0.w = fmaxf(o0.w, 0.f);
    o1.x = fmaxf(o1.x, 0.f); o1.y = fmaxf(o1.y, 0.f);
    o1.z = fmaxf(o1.z, 0.f); o1.w = fmaxf(o1.w, 0.f);
    if (node0 < N) *(float4*)(out + (size_t)node0 * D + q * 4) = o0;
    else o0 = make_float4(0.f, 0.f, 0.f, 0.f);
    if (node1 < N) *(float4*)(out + (size_t)node1 * D + q * 4) = o1;
    else o1 = make_float4(0.f, 0.f, 0.f, 0.f);
  }

  // ---- Optional epilogue: block-reduced BN stats (sum, sumsq) ----
  if (EMIT_STATS) {
    float s0 = o0.x + o1.x, s1 = o0.y + o1.y, s2 = o0.z + o1.z, s3 = o0.w + o1.w;
    float q0 = o0.x * o0.x + o1.x * o1.x, q1 = o0.y * o0.y + o1.y * o1.y;
    float q2 = o0.z * o0.z + o1.z * o1.z, q3 = o0.w * o0.w + o1.w * o1.w;
    __syncthreads();   // all s_in reads done; safe to reuse as reduce buffer
    *(float4*)&s_in[r2 * INP + q * 4] = make_float4(s0, s1, s2, s3);
    *(float4*)&s_in[(32 + r2) * INP + q * 4] = make_float4(q0, q1, q2, q3);
    __syncthreads();
#pragma unroll
    for (int s = 16; s >= 1; s >>= 1) {
      if (tid < 32 * s) {
        int h = tid / (16 * s);          // 0 = sum half, 1 = sq half
        int r = (tid / 16) % s;
        int qq = tid & 15;
        float4* a = (float4*)&s_in[(h * 32 + r) * INP + qq * 4];
        const float4 b = *(const float4*)&s_in[(h * 32 + r + s) * INP + qq * 4];
        a->x += b.x; a->y += b.y; a->z += b.z; a->w += b.w;
      }
      __syncthreads();
    }
    if (tid < D) {
      atomicAdd(&st_sum[tid], s_in[tid]);
      atomicAdd(&st_sq[tid], s_in[32 * INP + tid]);
    }
  }
}

// ---------------------------------------------------------------------------
// Fused global_mean_pool prep + BN2 stats: per-graph column sums & counts
// (run-length flush over sorted batch) + global column sum-of-squares.
// ---------------------------------------------------------------------------
__global__ void pool_stats_kernel(const float* __restrict__ h,
                                  const int* __restrict__ batch, int N,
                                  float* __restrict__ pool, float* __restrict__ cnt,
                                  float* __restrict__ sq) {
  __shared__ float lq[4 * D];
  int tid = threadIdx.x;
  int c = tid & (D - 1), w = tid >> 6;
  int chunk = (N + gridDim.x - 1) / gridDim.x;
  int r0 = blockIdx.x * chunk;
  int r1 = min(N, r0 + chunk);
  float acc = 0.f, lc = 0.f, qa = 0.f;
  int cur = -1;
  for (int r = r0 + w; r < r1; r += 4) {
    int g = batch[r];
    if (g != cur) {
      if (cur >= 0) {
        atomicAdd(&pool[cur * D + c], acc);
        if (c == 0) atomicAdd(&cnt[cur], lc);
      }
      cur = g; acc = 0.f; lc = 0.f;
    }
    float v = h[(size_t)r * D + c];
    acc += v; qa += v * v; lc += 1.f;
  }
  if (cur >= 0) {
    atomicAdd(&pool[cur * D + c], acc);
    if (c == 0) atomicAdd(&cnt[cur], lc);
  }
  lq[w * D + c] = qa;
  __syncthreads();
  if (tid < D)
    atomicAdd(&sq[c], lq[c] + lq[D + c] + lq[2 * D + c] + lq[3 * D + c]);
}

// ---------------------------------------------------------------------------
// Final: BN2 coeffs from (Σ_g pool, sq) + fused affine + mean divide.
// ---------------------------------------------------------------------------
__global__ void final_kernel(const float* __restrict__ pool,
                             const float* __restrict__ cnt,
                             const float* __restrict__ sq,
                             const float* __restrict__ gamma,
                             const float* __restrict__ beta,
                             float invN, float* __restrict__ out) {
  int c = threadIdx.x;   // 64 threads
  float s = 0.f;
#pragma unroll
  for (int g = 0; g < NG; g++) s += pool[g * D + c];
  float mean = s * invN;
  float var = sq[c] * invN - mean * mean;
  float a = gamma[c] * rsqrtf(var + 1e-5f);
  float b = beta[c] - mean * a;
#pragma unroll
  for (int g = 0; g < NG; g++) {
    float n = cnt[g];
    out[g * D + c] = (a * pool[g * D + c] + n * b) / fmaxf(n, 1.f);
  }
}

extern "C" void kernel_launch(void* const* d_in, const int* in_sizes, int n_in,
                              void* d_out, int out_size, void* d_ws, size_t ws_size,
                              hipStream_t stream) {
  const float* x   = (const float*)d_in[0];
  const int* ei    = (const int*)d_in[1];
  const int* batch = (const int*)d_in[2];
  const float* W1a = (const float*)d_in[5];
  const float* b1a = (const float*)d_in[6];
  const float* W1b = (const float*)d_in[7];
  const float* b1b = (const float*)d_in[8];
  const float* g1  = (const float*)d_in[9];
  const float* be1 = (const float*)d_in[10];
  const float* W2a = (const float*)d_in[11];
  const float* b2a = (const float*)d_in[12];
  const float* W2b = (const float*)d_in[13];
  const float* b2b = (const float*)d_in[14];
  const float* g2  = (const float*)d_in[15];
  const float* be2 = (const float*)d_in[16];

  int N = in_sizes[0] / D;        // 100000
  int E = in_sizes[1] / 2;        // 1600000
  int per = E / NG;               // 100000
  int tmul = N / NG;              // 6250
  float invN = 1.f / (float)N;

  float* ws = (float*)d_ws;
  size_t nd = (size_t)N * D;
  float* h1  = ws;                       // post-MLP1 (pre-BN; BN folded downstream)
  float* h2  = ws + nd;                  // post-MLP2 (pre-BN)
  int*   col = (int*)(ws + 2 * nd);      // CSR src lists (N*SLOT ints)
  float* stats = ws + 3 * nd;
  float* sum1 = stats;                   // 64
  float* sq1  = stats + 64;              // 64
  float* pool = stats + 128;             // 16*64
  float* cnt  = stats + 128 + NG * D;    // 16
  float* sq2  = stats + 144 + NG * D;    // 64
  int*   fill = (int*)(stats + 208 + NG * D);  // N ints (degree counts)

  hipMemsetAsync(stats, 0, (208 + NG * D + N) * sizeof(float), stream);

  build_csr_kernel<<<(E + 255) / 256, 256, 0, stream>>>(ei, fill, col, E, per, tmul);

  int fblocks = (N + 63) / 64;

  // Layer 1: gather(x) + MLP1 -> h1 (pre-BN) + BN1 stats epilogue
  fused_layer_kernel<32, false, true><<<fblocks, 512, 0, stream>>>(
      x, col, fill, nullptr, nullptr, nullptr, nullptr, invN,
      W1a, b1a, W1b, b1b, h1, sum1, sq1, N);

  // Layer 2: BN1 folded into gather input; -> h2 (pre-BN)
  fused_layer_kernel<64, true, false><<<fblocks, 512, 0, stream>>>(
      h1, col, fill, sum1, sq1, g1, be1, invN,
      W2a, b2a, W2b, b2b, h2, nullptr, nullptr, N);

  // Pool (per-graph sums+counts) + BN2 sumsq in one pass.
  pool_stats_kernel<<<1024, 256, 0, stream>>>(h2, batch, N, pool, cnt, sq2);

  // BN2 coeffs + affine + mean.
  final_kernel<<<1, 64, 0, stream>>>(pool, cnt, sq2, g2, be2, invN, (float*)d_out);
}

// Round 6
// 1528.820 us; speedup vs baseline: 1.3107x; 1.3107x over previous
//
#include <hip/hip_runtime.h>

#define NG 16     // num_graphs (fixed by problem)
#define D 64      // feature width at every aggregation point
#define SLOT 64   // CSR slots per node; in-degree <= ~Poisson(8.5), P(>=64) negligible

// ---------------------------------------------------------------------------
// Build fixed-stride CSR by destination. One int atomic per VALID edge.
// ---------------------------------------------------------------------------
__global__ void build_csr_kernel(const int* __restrict__ ei,
                                 int* __restrict__ fill,
                                 int* __restrict__ col,
                                 int E, int per, int tmul) {
  int e = blockIdx.x * blockDim.x + threadIdx.x;
  if (e >= E) return;
  int src = ei[e];
  int dst = ei[E + e];
  int g = e / per;            // compiler magic-div
  int thr = g * tmul;
  if (src >= thr && dst >= thr) {
    int k = atomicAdd(&fill[dst], 1);
    if (k < SLOT) col[dst * SLOT + k] = src;   // clamp is paranoia-only
  }
}

// ---------------------------------------------------------------------------
// Fused layer: gather + (optional BN fold) + 2-linear MLP (+ optional BN-stats
// epilogue). Block = 512 threads, 64 nodes.
//  Phase A: 16 lanes/node, float4 gathers -> s_in.
//  Phase B: thread (q,r2) computes nodes {2r2,2r2+1} x its cols. Stage-1
//           results stay in registers; stage 2 broadcasts them via 16-lane
//           __shfl (no s_mid). Wb read from global (L1-resident, coalesced).
//  LDS = s_in + Wa only (34 KB) -> up to 4 blocks/CU when VGPR <= 64.
//  NOTE: __launch_bounds__ 2nd arg = min waves per EU. 8 forced VGPR<=32 and
//  caused catastrophic scratch spilling (R5: 2.3GB FETCH). Keep 4.
// ---------------------------------------------------------------------------
template <int MID, bool FOLD_BN, bool EMIT_STATS>
__global__ __launch_bounds__(512, 4) void fused_layer_kernel(
    const float* __restrict__ feat, const int* __restrict__ col,
    const int* __restrict__ deg,
    const float* __restrict__ bn_sum, const float* __restrict__ bn_sq,
    const float* __restrict__ bn_gamma, const float* __restrict__ bn_beta,
    float invN,
    const float* __restrict__ Wa, const float* __restrict__ ba,
    const float* __restrict__ Wb, const float* __restrict__ bb,
    float* __restrict__ out,
    float* __restrict__ st_sum, float* __restrict__ st_sq, int N) {
  constexpr int NPB = 64;        // nodes per block
  constexpr int INP = D + 4;     // padded row stride (272B = 17 float4s, conflict-free)
  __shared__ float s_in[NPB * INP];
  __shared__ float s_Wa[D * MID];
  __shared__ float s_bna[FOLD_BN ? D : 1];
  __shared__ float s_bnb[FOLD_BN ? D : 1];

  int tid = threadIdx.x;

  // Stage Wa (coalesced float4, once per block).
  {
    const float4* wa4 = (const float4*)Wa;
    float4* sa4 = (float4*)s_Wa;
    constexpr int NW = D * MID / 4;
#pragma unroll
    for (int i = tid; i < NW; i += 512) sa4[i] = wa4[i];
  }
  if (FOLD_BN && tid < D) {
    float mean = bn_sum[tid] * invN;
    float var = bn_sq[tid] * invN - mean * mean;
    float av = bn_gamma[tid] * rsqrtf(var + 1e-5f);
    s_bna[tid] = av;
    s_bnb[tid] = bn_beta[tid] - mean * av;
  }
  __syncthreads();

  int q = tid & 15;               // lane within 16-group
  int base = blockIdx.x * NPB;

  // ---- Phase A: gather + self + optional BN fold -> LDS rows ----
  {
    int ns = tid >> 4;            // 0..31
#pragma unroll
    for (int pass = 0; pass < 2; pass++) {
      int slot = ns + 32 * pass;
      int node = base + slot;
      if (node < N) {
        int d = min(deg[node], SLOT);
        const int* cl = col + node * SLOT;
        float4 acc = *(const float4*)(feat + (size_t)node * D + q * 4);  // self
        int j = 0;
        for (; j + 4 <= d; j += 4) {
          int4 s4 = *(const int4*)(cl + j);
          float4 v0 = *(const float4*)(feat + (size_t)s4.x * D + q * 4);
          float4 v1 = *(const float4*)(feat + (size_t)s4.y * D + q * 4);
          float4 v2 = *(const float4*)(feat + (size_t)s4.z * D + q * 4);
          float4 v3 = *(const float4*)(feat + (size_t)s4.w * D + q * 4);
          acc.x += v0.x + v1.x + v2.x + v3.x;
          acc.y += v0.y + v1.y + v2.y + v3.y;
          acc.z += v0.z + v1.z + v2.z + v3.z;
          acc.w += v0.w + v1.w + v2.w + v3.w;
        }
        for (; j < d; j++) {
          int s = cl[j];
          float4 v = *(const float4*)(feat + (size_t)s * D + q * 4);
          acc.x += v.x; acc.y += v.y; acc.z += v.z; acc.w += v.w;
        }
        if (FOLD_BN) {
          float dp = (float)(d + 1);
          int c = q * 4;
          acc.x = s_bna[c + 0] * acc.x + dp * s_bnb[c + 0];
          acc.y = s_bna[c + 1] * acc.y + dp * s_bnb[c + 1];
          acc.z = s_bna[c + 2] * acc.z + dp * s_bnb[c + 2];
          acc.w = s_bna[c + 3] * acc.w + dp * s_bnb[c + 3];
        }
        *(float4*)&s_in[slot * INP + q * 4] = acc;
      }
    }
  }
  __syncthreads();

  // ---- Phase B: register-tiled MLP, s_mid replaced by 16-lane shuffles ----
  int r2 = tid >> 4;              // 0..31 -> nodes 2r2, 2r2+1
  int n0 = 2 * r2, n1 = n0 + 1;
  constexpr int C1 = MID / 16;    // stage-1 cols per thread (2 or 4)
  float4 o0, o1;
  {
    // stage 1: mid = relu(in @ Wa + ba), kept in registers
    float acc0[C1], acc1[C1];
#pragma unroll
    for (int u = 0; u < C1; u++) { acc0[u] = ba[q * C1 + u]; acc1[u] = acc0[u]; }
#pragma unroll 4
    for (int j = 0; j < D; j++) {
      float v0 = s_in[n0 * INP + j];
      float v1 = s_in[n1 * INP + j];
#pragma unroll
      for (int u = 0; u < C1; u++) {
        float w = s_Wa[j * MID + q * C1 + u];   // b64/b128, group-broadcast
        acc0[u] += v0 * w;
        acc1[u] += v1 * w;
      }
    }
#pragma unroll
    for (int u = 0; u < C1; u++) {
      acc0[u] = fmaxf(acc0[u], 0.f);
      acc1[u] = fmaxf(acc1[u], 0.f);
    }

    // stage 2: out cols 4q..4q+3; mid[k] owner lane = k/C1, reg = k%C1
    const float4* wb4 = (const float4*)Wb;
    o0 = *(const float4*)(bb + q * 4);
    o1 = o0;
#pragma unroll
    for (int k = 0; k < MID; k++) {
      float m0 = __shfl(acc0[k % C1], k / C1, 16);
      float m1 = __shfl(acc1[k % C1], k / C1, 16);
      float4 w = wb4[k * 16 + q];               // global: coalesced, L1-hot
      o0.x += m0 * w.x; o0.y += m0 * w.y; o0.z += m0 * w.z; o0.w += m0 * w.w;
      o1.x += m1 * w.x; o1.y += m1 * w.y; o1.z += m1 * w.z; o1.w += m1 * w.w;
    }
    int node0 = base + n0, node1 = base + n1;
    o0.x = fmaxf(o0.x, 0.f); o0.y = fmaxf(o0.y, 0.f);
    o0.z = fmaxf(o0.z, 0.f); o0.w = fmaxf(o0.w, 0.f);
    o1.x = fmaxf(o1.x, 0.f); o1.y = fmaxf(o1.y, 0.f);
    o1.z = fmaxf(o1.z, 0.f); o1.w = fmaxf(o1.w, 0.f);
    if (node0 < N) *(float4*)(out + (size_t)node0 * D + q * 4) = o0;
    else o0 = make_float4(0.f, 0.f, 0.f, 0.f);
    if (node1 < N) *(float4*)(out + (size_t)node1 * D + q * 4) = o1;
    else o1 = make_float4(0.f, 0.f, 0.f, 0.f);
  }

  // ---- Optional epilogue: block-reduced BN stats (sum, sumsq) ----
  if (EMIT_STATS) {
    float s0 = o0.x + o1.x, s1 = o0.y + o1.y, s2 = o0.z + o1.z, s3 = o0.w + o1.w;
    float q0 = o0.x * o0.x + o1.x * o1.x, q1 = o0.y * o0.y + o1.y * o1.y;
    float q2 = o0.z * o0.z + o1.z * o1.z, q3 = o0.w * o0.w + o1.w * o1.w;
    __syncthreads();   // all s_in reads done; safe to reuse as reduce buffer
    *(float4*)&s_in[r2 * INP + q * 4] = make_float4(s0, s1, s2, s3);
    *(float4*)&s_in[(32 + r2) * INP + q * 4] = make_float4(q0, q1, q2, q3);
    __syncthreads();
#pragma unroll
    for (int s = 16; s >= 1; s >>= 1) {
      if (tid < 32 * s) {
        int h = tid / (16 * s);          // 0 = sum half, 1 = sq half
        int r = (tid / 16) % s;
        int qq = tid & 15;
        float4* a = (float4*)&s_in[(h * 32 + r) * INP + qq * 4];
        const float4 b = *(const float4*)&s_in[(h * 32 + r + s) * INP + qq * 4];
        a->x += b.x; a->y += b.y; a->z += b.z; a->w += b.w;
      }
      __syncthreads();
    }
    if (tid < D) {
      atomicAdd(&st_sum[tid], s_in[tid]);
      atomicAdd(&st_sq[tid], s_in[32 * INP + tid]);
    }
  }
}

// ---------------------------------------------------------------------------
// Fused global_mean_pool prep + BN2 stats: per-graph column sums & counts
// (run-length flush over sorted batch) + global column sum-of-squares.
// ---------------------------------------------------------------------------
__global__ void pool_stats_kernel(const float* __restrict__ h,
                                  const int* __restrict__ batch, int N,
                                  float* __restrict__ pool, float* __restrict__ cnt,
                                  float* __restrict__ sq) {
  __shared__ float lq[4 * D];
  int tid = threadIdx.x;
  int c = tid & (D - 1), w = tid >> 6;
  int chunk = (N + gridDim.x - 1) / gridDim.x;
  int r0 = blockIdx.x * chunk;
  int r1 = min(N, r0 + chunk);
  float acc = 0.f, lc = 0.f, qa = 0.f;
  int cur = -1;
  for (int r = r0 + w; r < r1; r += 4) {
    int g = batch[r];
    if (g != cur) {
      if (cur >= 0) {
        atomicAdd(&pool[cur * D + c], acc);
        if (c == 0) atomicAdd(&cnt[cur], lc);
      }
      cur = g; acc = 0.f; lc = 0.f;
    }
    float v = h[(size_t)r * D + c];
    acc += v; qa += v * v; lc += 1.f;
  }
  if (cur >= 0) {
    atomicAdd(&pool[cur * D + c], acc);
    if (c == 0) atomicAdd(&cnt[cur], lc);
  }
  lq[w * D + c] = qa;
  __syncthreads();
  if (tid < D)
    atomicAdd(&sq[c], lq[c] + lq[D + c] + lq[2 * D + c] + lq[3 * D + c]);
}

// ---------------------------------------------------------------------------
// Final: BN2 coeffs from (Σ_g pool, sq) + fused affine + mean divide.
// ---------------------------------------------------------------------------
__global__ void final_kernel(const float* __restrict__ pool,
                             const float* __restrict__ cnt,
                             const float* __restrict__ sq,
                             const float* __restrict__ gamma,
                             const float* __restrict__ beta,
                             float invN, float* __restrict__ out) {
  int c = threadIdx.x;   // 64 threads
  float s = 0.f;
#pragma unroll
  for (int g = 0; g < NG; g++) s += pool[g * D + c];
  float mean = s * invN;
  float var = sq[c] * invN - mean * mean;
  float a = gamma[c] * rsqrtf(var + 1e-5f);
  float b = beta[c] - mean * a;
#pragma unroll
  for (int g = 0; g < NG; g++) {
    float n = cnt[g];
    out[g * D + c] = (a * pool[g * D + c] + n * b) / fmaxf(n, 1.f);
  }
}

extern "C" void kernel_launch(void* const* d_in, const int* in_sizes, int n_in,
                              void* d_out, int out_size, void* d_ws, size_t ws_size,
                              hipStream_t stream) {
  const float* x   = (const float*)d_in[0];
  const int* ei    = (const int*)d_in[1];
  const int* batch = (const int*)d_in[2];
  const float* W1a = (const float*)d_in[5];
  const float* b1a = (const float*)d_in[6];
  const float* W1b = (const float*)d_in[7];
  const float* b1b = (const float*)d_in[8];
  const float* g1  = (const float*)d_in[9];
  const float* be1 = (const float*)d_in[10];
  const float* W2a = (const float*)d_in[11];
  const float* b2a = (const float*)d_in[12];
  const float* W2b = (const float*)d_in[13];
  const float* b2b = (const float*)d_in[14];
  const float* g2  = (const float*)d_in[15];
  const float* be2 = (const float*)d_in[16];

  int N = in_sizes[0] / D;        // 100000
  int E = in_sizes[1] / 2;        // 1600000
  int per = E / NG;               // 100000
  int tmul = N / NG;              // 6250
  float invN = 1.f / (float)N;

  float* ws = (float*)d_ws;
  size_t nd = (size_t)N * D;
  float* h1  = ws;                       // post-MLP1 (pre-BN; BN folded downstream)
  float* h2  = ws + nd;                  // post-MLP2 (pre-BN)
  int*   col = (int*)(ws + 2 * nd);      // CSR src lists (N*SLOT ints)
  float* stats = ws + 3 * nd;
  float* sum1 = stats;                   // 64
  float* sq1  = stats + 64;              // 64
  float* pool = stats + 128;             // 16*64
  float* cnt  = stats + 128 + NG * D;    // 16
  float* sq2  = stats + 144 + NG * D;    // 64
  int*   fill = (int*)(stats + 208 + NG * D);  // N ints (degree counts)

  hipMemsetAsync(stats, 0, (208 + NG * D + N) * sizeof(float), stream);

  build_csr_kernel<<<(E + 255) / 256, 256, 0, stream>>>(ei, fill, col, E, per, tmul);

  int fblocks = (N + 63) / 64;

  // Layer 1: gather(x) + MLP1 -> h1 (pre-BN) + BN1 stats epilogue
  fused_layer_kernel<32, false, true><<<fblocks, 512, 0, stream>>>(
      x, col, fill, nullptr, nullptr, nullptr, nullptr, invN,
      W1a, b1a, W1b, b1b, h1, sum1, sq1, N);

  // Layer 2: BN1 folded into gather input; -> h2 (pre-BN)
  fused_layer_kernel<64, true, false><<<fblocks, 512, 0, stream>>>(
      h1, col, fill, sum1, sq1, g1, be1, invN,
      W2a, b2a, W2b, b2b, h2, nullptr, nullptr, N);

  // Pool (per-graph sums+counts) + BN2 sumsq in one pass.
  pool_stats_kernel<<<1024, 256, 0, stream>>>(h2, batch, N, pool, cnt, sq2);

  // BN2 coeffs + affine + mean.
  final_kernel<<<1, 64, 0, stream>>>(pool, cnt, sq2, g2, be2, invN, (float*)d_out);
}

// Round 7
// 330.120 us; speedup vs baseline: 6.0701x; 4.6311x over previous
//
#include <hip/hip_runtime.h>

#define NG 16     // num_graphs (fixed by problem)
#define D 64      // feature width at every aggregation point
#define SLOT 64   // CSR slots per node; in-degree <= ~Poisson(8.5), P(>=64) negligible

// ---------------------------------------------------------------------------
// Build fixed-stride CSR by destination. One int atomic per VALID edge.
// ---------------------------------------------------------------------------
__global__ void build_csr_kernel(const int* __restrict__ ei,
                                 int* __restrict__ fill,
                                 int* __restrict__ col,
                                 int E, int per, int tmul) {
  int e = blockIdx.x * blockDim.x + threadIdx.x;
  if (e >= E) return;
  int src = ei[e];
  int dst = ei[E + e];
  int g = e / per;            // compiler magic-div
  int thr = g * tmul;
  if (src >= thr && dst >= thr) {
    int k = atomicAdd(&fill[dst], 1);
    if (k < SLOT) col[dst * SLOT + k] = src;   // clamp is paranoia-only
  }
}

// ---------------------------------------------------------------------------
// Fused layer: gather + (optional BN fold) + 2-linear MLP (+ optional BN-stats
// epilogue). Block = 512 threads, 64 nodes.
//  Phase A: 16 lanes/node, float4 gathers -> s_in.
//  Phase B: thread (q,r2) computes nodes {2r2,2r2+1} x its cols. Stage-1
//           results stay in registers; stage 2 broadcasts them via 16-lane
//           __shfl (no s_mid). Wb read from global (L1-resident, coalesced),
//           k-loop unroll capped at 8 to bound in-flight load registers.
//  LDS = s_in + Wa only (34 KB).
//  __launch_bounds__ 2nd arg (empirical, 512-thr blocks): VGPR cap = 256/arg.
//    arg=8 -> cap 32 (R5 spill disaster), arg=4 -> cap 64 (R6 spill),
//    arg=2 -> cap 128 (no spill; LDS still allows >=3 blocks/CU).
// ---------------------------------------------------------------------------
template <int MID, bool FOLD_BN, bool EMIT_STATS>
__global__ __launch_bounds__(512, 2) void fused_layer_kernel(
    const float* __restrict__ feat, const int* __restrict__ col,
    const int* __restrict__ deg,
    const float* __restrict__ bn_sum, const float* __restrict__ bn_sq,
    const float* __restrict__ bn_gamma, const float* __restrict__ bn_beta,
    float invN,
    const float* __restrict__ Wa, const float* __restrict__ ba,
    const float* __restrict__ Wb, const float* __restrict__ bb,
    float* __restrict__ out,
    float* __restrict__ st_sum, float* __restrict__ st_sq, int N) {
  constexpr int NPB = 64;        // nodes per block
  constexpr int INP = D + 4;     // padded row stride (272B = 17 float4s, conflict-free)
  __shared__ float s_in[NPB * INP];
  __shared__ float s_Wa[D * MID];
  __shared__ float s_bna[FOLD_BN ? D : 1];
  __shared__ float s_bnb[FOLD_BN ? D : 1];

  int tid = threadIdx.x;

  // Stage Wa (coalesced float4, once per block).
  {
    const float4* wa4 = (const float4*)Wa;
    float4* sa4 = (float4*)s_Wa;
    constexpr int NW = D * MID / 4;
#pragma unroll
    for (int i = tid; i < NW; i += 512) sa4[i] = wa4[i];
  }
  if (FOLD_BN && tid < D) {
    float mean = bn_sum[tid] * invN;
    float var = bn_sq[tid] * invN - mean * mean;
    float av = bn_gamma[tid] * rsqrtf(var + 1e-5f);
    s_bna[tid] = av;
    s_bnb[tid] = bn_beta[tid] - mean * av;
  }
  __syncthreads();

  int q = tid & 15;               // lane within 16-group
  int base = blockIdx.x * NPB;

  // ---- Phase A: gather + self + optional BN fold -> LDS rows ----
  {
    int ns = tid >> 4;            // 0..31
#pragma unroll
    for (int pass = 0; pass < 2; pass++) {
      int slot = ns + 32 * pass;
      int node = base + slot;
      if (node < N) {
        int d = min(deg[node], SLOT);
        const int* cl = col + node * SLOT;
        float4 acc = *(const float4*)(feat + (size_t)node * D + q * 4);  // self
        int j = 0;
        for (; j + 4 <= d; j += 4) {
          int4 s4 = *(const int4*)(cl + j);
          float4 v0 = *(const float4*)(feat + (size_t)s4.x * D + q * 4);
          float4 v1 = *(const float4*)(feat + (size_t)s4.y * D + q * 4);
          float4 v2 = *(const float4*)(feat + (size_t)s4.z * D + q * 4);
          float4 v3 = *(const float4*)(feat + (size_t)s4.w * D + q * 4);
          acc.x += v0.x + v1.x + v2.x + v3.x;
          acc.y += v0.y + v1.y + v2.y + v3.y;
          acc.z += v0.z + v1.z + v2.z + v3.z;
          acc.w += v0.w + v1.w + v2.w + v3.w;
        }
        for (; j < d; j++) {
          int s = cl[j];
          float4 v = *(const float4*)(feat + (size_t)s * D + q * 4);
          acc.x += v.x; acc.y += v.y; acc.z += v.z; acc.w += v.w;
        }
        if (FOLD_BN) {
          float dp = (float)(d + 1);
          int c = q * 4;
          acc.x = s_bna[c + 0] * acc.x + dp * s_bnb[c + 0];
          acc.y = s_bna[c + 1] * acc.y + dp * s_bnb[c + 1];
          acc.z = s_bna[c + 2] * acc.z + dp * s_bnb[c + 2];
          acc.w = s_bna[c + 3] * acc.w + dp * s_bnb[c + 3];
        }
        *(float4*)&s_in[slot * INP + q * 4] = acc;
      }
    }
  }
  __syncthreads();

  // ---- Phase B: register-tiled MLP, s_mid replaced by 16-lane shuffles ----
  int r2 = tid >> 4;              // 0..31 -> nodes 2r2, 2r2+1
  int n0 = 2 * r2, n1 = n0 + 1;
  constexpr int C1 = MID / 16;    // stage-1 cols per thread (2 or 4)
  float4 o0, o1;
  {
    // stage 1: mid = relu(in @ Wa + ba), kept in registers
    float acc0[C1], acc1[C1];
#pragma unroll
    for (int u = 0; u < C1; u++) { acc0[u] = ba[q * C1 + u]; acc1[u] = acc0[u]; }
#pragma unroll 4
    for (int j = 0; j < D; j++) {
      float v0 = s_in[n0 * INP + j];
      float v1 = s_in[n1 * INP + j];
#pragma unroll
      for (int u = 0; u < C1; u++) {
        float w = s_Wa[j * MID + q * C1 + u];   // b64/b128, group-broadcast
        acc0[u] += v0 * w;
        acc1[u] += v1 * w;
      }
    }
#pragma unroll
    for (int u = 0; u < C1; u++) {
      acc0[u] = fmaxf(acc0[u], 0.f);
      acc1[u] = fmaxf(acc1[u], 0.f);
    }

    // stage 2: out cols 4q..4q+3; mid[k] owner lane = k/C1, reg = k%C1
    // unroll capped at 8: full unroll kept ~64 float4 Wb loads in flight ->
    // register-demand blowup -> spill (R5/R6).
    const float4* wb4 = (const float4*)Wb;
    o0 = *(const float4*)(bb + q * 4);
    o1 = o0;
#pragma unroll 8
    for (int k = 0; k < MID; k++) {
      float m0 = __shfl(acc0[k % C1], k / C1, 16);
      float m1 = __shfl(acc1[k % C1], k / C1, 16);
      float4 w = wb4[k * 16 + q];               // global: coalesced, L1-hot
      o0.x += m0 * w.x; o0.y += m0 * w.y; o0.z += m0 * w.z; o0.w += m0 * w.w;
      o1.x += m1 * w.x; o1.y += m1 * w.y; o1.z += m1 * w.z; o1.w += m1 * w.w;
    }
    int node0 = base + n0, node1 = base + n1;
    o0.x = fmaxf(o0.x, 0.f); o0.y = fmaxf(o0.y, 0.f);
    o0.z = fmaxf(o0.z, 0.f); o0.w = fmaxf(o0.w, 0.f);
    o1.x = fmaxf(o1.x, 0.f); o1.y = fmaxf(o1.y, 0.f);
    o1.z = fmaxf(o1.z, 0.f); o1.w = fmaxf(o1.w, 0.f);
    if (node0 < N) *(float4*)(out + (size_t)node0 * D + q * 4) = o0;
    else o0 = make_float4(0.f, 0.f, 0.f, 0.f);
    if (node1 < N) *(float4*)(out + (size_t)node1 * D + q * 4) = o1;
    else o1 = make_float4(0.f, 0.f, 0.f, 0.f);
  }

  // ---- Optional epilogue: block-reduced BN stats (sum, sumsq) ----
  if (EMIT_STATS) {
    float s0 = o0.x + o1.x, s1 = o0.y + o1.y, s2 = o0.z + o1.z, s3 = o0.w + o1.w;
    float q0 = o0.x * o0.x + o1.x * o1.x, q1 = o0.y * o0.y + o1.y * o1.y;
    float q2 = o0.z * o0.z + o1.z * o1.z, q3 = o0.w * o0.w + o1.w * o1.w;
    __syncthreads();   // all s_in reads done; safe to reuse as reduce buffer
    *(float4*)&s_in[r2 * INP + q * 4] = make_float4(s0, s1, s2, s3);
    *(float4*)&s_in[(32 + r2) * INP + q * 4] = make_float4(q0, q1, q2, q3);
    __syncthreads();
#pragma unroll
    for (int s = 16; s >= 1; s >>= 1) {
      if (tid < 32 * s) {
        int h = tid / (16 * s);          // 0 = sum half, 1 = sq half
        int r = (tid / 16) % s;
        int qq = tid & 15;
        float4* a = (float4*)&s_in[(h * 32 + r) * INP + qq * 4];
        const float4 b = *(const float4*)&s_in[(h * 32 + r + s) * INP + qq * 4];
        a->x += b.x; a->y += b.y; a->z += b.z; a->w += b.w;
      }
      __syncthreads();
    }
    if (tid < D) {
      atomicAdd(&st_sum[tid], s_in[tid]);
      atomicAdd(&st_sq[tid], s_in[32 * INP + tid]);
    }
  }
}

// ---------------------------------------------------------------------------
// Fused global_mean_pool prep + BN2 stats: per-graph column sums & counts
// (run-length flush over sorted batch) + global column sum-of-squares.
// ---------------------------------------------------------------------------
__global__ void pool_stats_kernel(const float* __restrict__ h,
                                  const int* __restrict__ batch, int N,
                                  float* __restrict__ pool, float* __restrict__ cnt,
                                  float* __restrict__ sq) {
  __shared__ float lq[4 * D];
  int tid = threadIdx.x;
  int c = tid & (D - 1), w = tid >> 6;
  int chunk = (N + gridDim.x - 1) / gridDim.x;
  int r0 = blockIdx.x * chunk;
  int r1 = min(N, r0 + chunk);
  float acc = 0.f, lc = 0.f, qa = 0.f;
  int cur = -1;
  for (int r = r0 + w; r < r1; r += 4) {
    int g = batch[r];
    if (g != cur) {
      if (cur >= 0) {
        atomicAdd(&pool[cur * D + c], acc);
        if (c == 0) atomicAdd(&cnt[cur], lc);
      }
      cur = g; acc = 0.f; lc = 0.f;
    }
    float v = h[(size_t)r * D + c];
    acc += v; qa += v * v; lc += 1.f;
  }
  if (cur >= 0) {
    atomicAdd(&pool[cur * D + c], acc);
    if (c == 0) atomicAdd(&cnt[cur], lc);
  }
  lq[w * D + c] = qa;
  __syncthreads();
  if (tid < D)
    atomicAdd(&sq[c], lq[c] + lq[D + c] + lq[2 * D + c] + lq[3 * D + c]);
}

// ---------------------------------------------------------------------------
// Final: BN2 coeffs from (Σ_g pool, sq) + fused affine + mean divide.
// ---------------------------------------------------------------------------
__global__ void final_kernel(const float* __restrict__ pool,
                             const float* __restrict__ cnt,
                             const float* __restrict__ sq,
                             const float* __restrict__ gamma,
                             const float* __restrict__ beta,
                             float invN, float* __restrict__ out) {
  int c = threadIdx.x;   // 64 threads
  float s = 0.f;
#pragma unroll
  for (int g = 0; g < NG; g++) s += pool[g * D + c];
  float mean = s * invN;
  float var = sq[c] * invN - mean * mean;
  float a = gamma[c] * rsqrtf(var + 1e-5f);
  float b = beta[c] - mean * a;
#pragma unroll
  for (int g = 0; g < NG; g++) {
    float n = cnt[g];
    out[g * D + c] = (a * pool[g * D + c] + n * b) / fmaxf(n, 1.f);
  }
}

extern "C" void kernel_launch(void* const* d_in, const int* in_sizes, int n_in,
                              void* d_out, int out_size, void* d_ws, size_t ws_size,
                              hipStream_t stream) {
  const float* x   = (const float*)d_in[0];
  const int* ei    = (const int*)d_in[1];
  const int* batch = (const int*)d_in[2];
  const float* W1a = (const float*)d_in[5];
  const float* b1a = (const float*)d_in[6];
  const float* W1b = (const float*)d_in[7];
  const float* b1b = (const float*)d_in[8];
  const float* g1  = (const float*)d_in[9];
  const float* be1 = (const float*)d_in[10];
  const float* W2a = (const float*)d_in[11];
  const float* b2a = (const float*)d_in[12];
  const float* W2b = (const float*)d_in[13];
  const float* b2b = (const float*)d_in[14];
  const float* g2  = (const float*)d_in[15];
  const float* be2 = (const float*)d_in[16];

  int N = in_sizes[0] / D;        // 100000
  int E = in_sizes[1] / 2;        // 1600000
  int per = E / NG;               // 100000
  int tmul = N / NG;              // 6250
  float invN = 1.f / (float)N;

  float* ws = (float*)d_ws;
  size_t nd = (size_t)N * D;
  float* h1  = ws;                       // post-MLP1 (pre-BN; BN folded downstream)
  float* h2  = ws + nd;                  // post-MLP2 (pre-BN)
  int*   col = (int*)(ws + 2 * nd);      // CSR src lists (N*SLOT ints)
  float* stats = ws + 3 * nd;
  float* sum1 = stats;                   // 64
  float* sq1  = stats + 64;              // 64
  float* pool = stats + 128;             // 16*64
  float* cnt  = stats + 128 + NG * D;    // 16
  float* sq2  = stats + 144 + NG * D;    // 64
  int*   fill = (int*)(stats + 208 + NG * D);  // N ints (degree counts)

  hipMemsetAsync(stats, 0, (208 + NG * D + N) * sizeof(float), stream);

  build_csr_kernel<<<(E + 255) / 256, 256, 0, stream>>>(ei, fill, col, E, per, tmul);

  int fblocks = (N + 63) / 64;

  // Layer 1: gather(x) + MLP1 -> h1 (pre-BN) + BN1 stats epilogue
  fused_layer_kernel<32, false, true><<<fblocks, 512, 0, stream>>>(
      x, col, fill, nullptr, nullptr, nullptr, nullptr, invN,
      W1a, b1a, W1b, b1b, h1, sum1, sq1, N);

  // Layer 2: BN1 folded into gather input; -> h2 (pre-BN)
  fused_layer_kernel<64, true, false><<<fblocks, 512, 0, stream>>>(
      h1, col, fill, sum1, sq1, g1, be1, invN,
      W2a, b2a, W2b, b2b, h2, nullptr, nullptr, N);

  // Pool (per-graph sums+counts) + BN2 sumsq in one pass.
  pool_stats_kernel<<<1024, 256, 0, stream>>>(h2, batch, N, pool, cnt, sq2);

  // BN2 coeffs + affine + mean.
  final_kernel<<<1, 64, 0, stream>>>(pool, cnt, sq2, g2, be2, invN, (float*)d_out);
}

// Round 9
// 286.270 us; speedup vs baseline: 6.9999x; 1.1532x over previous
//
#include <hip/hip_runtime.h>

#define NG 16     // num_graphs (fixed by problem)
#define D 64      // feature width at every aggregation point
#define SLOT 64   // CSR slots per node; max in-degree ~Poisson(8.5), P(>=64) negligible
#define INP 68    // padded LDS row stride (D+4): float4-aligned, conflict-free

// ---------------------------------------------------------------------------
// Build fixed-stride CSR by destination. One int atomic per VALID edge.
// ---------------------------------------------------------------------------
__global__ void build_csr_kernel(const int* __restrict__ ei,
                                 int* __restrict__ fill,
                                 int* __restrict__ col,
                                 int E, int per, int tmul) {
  int e = blockIdx.x * blockDim.x + threadIdx.x;
  if (e >= E) return;
  int src = ei[e];
  int dst = ei[E + e];
  int g = e / per;            // compiler magic-div
  int thr = g * tmul;
  if (src >= thr && dst >= thr) {
    int k = atomicAdd(&fill[dst], 1);
    if (k < SLOT) col[dst * SLOT + k] = src;   // clamp is paranoia-only
  }
}

// Tree-reduce rows 0..31 (+32..63 as a second half) of s_in down to row 0 /
// row 32. Operates on 64 float columns per half, float4 per lane.
__device__ __forceinline__ void tree_reduce_2x32(float* s_in, int tid) {
#pragma unroll
  for (int s = 16; s >= 1; s >>= 1) {
    if (tid < 32 * s) {
      int h = tid / (16 * s);          // 0 = first half, 1 = second half
      int r = (tid / 16) % s;
      int qq = tid & 15;
      float4* a = (float4*)&s_in[(h * 32 + r) * INP + qq * 4];
      const float4 b = *(const float4*)&s_in[(h * 32 + r + s) * INP + qq * 4];
      a->x += b.x; a->y += b.y; a->z += b.z; a->w += b.w;
    }
    __syncthreads();
  }
}

// ---------------------------------------------------------------------------
// Fused layer: gather + (optional BN fold) + 2-linear MLP + epilogue.
//  EPI==1 (layer 1): store h to `out`, block-reduce BN stats (sum, sumsq).
//  EPI==2 (layer 2): NO per-node store. Pool per-graph sums (sorted batch ->
//    <=2 graphs per 64-node block; masked tree-reduce per graph) + global
//    sumsq + counts. h2 never touches HBM.
// Block = 512 threads, 64 nodes. Phase A: 16 lanes/node float4 gathers.
// Phase B: thread (q,r2) -> nodes {2r2,2r2+1}; stage-1 mids in registers,
// stage-2 broadcasts via 16-lane __shfl; Wa AND Wb staged in LDS.
// __launch_bounds__ 2nd arg (empirical, 512-thr blocks): VGPR cap = 256/arg.
//   arg=8 -> 32 (R5 spill), arg=4 -> 64 (R6 spill), arg=2 -> 128 (safe).
// R8 bug fixed here: s_cnt was incremented by all 16 q-lanes of each
// r2-group (same two nodes) -> counts 16x too big. Only q==0 contributes.
// ---------------------------------------------------------------------------
template <int MID, bool FOLD_BN, int EPI>
__global__ __launch_bounds__(512, 2) void fused_layer_kernel(
    const float* __restrict__ feat, const int* __restrict__ col,
    const int* __restrict__ deg,
    const float* __restrict__ bn_sum, const float* __restrict__ bn_sq,
    const float* __restrict__ bn_gamma, const float* __restrict__ bn_beta,
    float invN,
    const float* __restrict__ Wa, const float* __restrict__ ba,
    const float* __restrict__ Wb, const float* __restrict__ bb,
    float* __restrict__ out,            // EPI==1 only
    const int* __restrict__ batch,      // EPI==2 only
    float* __restrict__ st_sum,         // EPI==1: sum[64]; EPI==2: pool[NG*64]
    float* __restrict__ st_sq,          // sumsq[64]
    float* __restrict__ cnt,            // EPI==2 only: per-graph counts
    int N) {
  constexpr int NPB = 64;        // nodes per block
  __shared__ float s_in[NPB * INP];
  __shared__ float s_Wa[D * MID];
  __shared__ float s_Wb[MID * D];
  __shared__ float s_bna[FOLD_BN ? D : 1];
  __shared__ float s_bnb[FOLD_BN ? D : 1];
  __shared__ int s_cnt[2];

  int tid = threadIdx.x;

  // Stage Wa+Wb (coalesced float4, once per block).
  {
    const float4* wa4 = (const float4*)Wa;
    const float4* wb4 = (const float4*)Wb;
    float4* sa4 = (float4*)s_Wa;
    float4* sb4 = (float4*)s_Wb;
    constexpr int NW = D * MID / 4;
#pragma unroll
    for (int i = tid; i < NW; i += 512) { sa4[i] = wa4[i]; sb4[i] = wb4[i]; }
  }
  if (FOLD_BN && tid < D) {
    float mean = bn_sum[tid] * invN;
    float var = bn_sq[tid] * invN - mean * mean;
    float av = bn_gamma[tid] * rsqrtf(var + 1e-5f);
    s_bna[tid] = av;
    s_bnb[tid] = bn_beta[tid] - mean * av;
  }
  if (EPI == 2 && tid < 2) s_cnt[tid] = 0;
  __syncthreads();

  int q = tid & 15;               // lane within 16-group
  int base = blockIdx.x * NPB;

  // ---- Phase A: gather + self + optional BN fold -> LDS rows ----
  {
    int ns = tid >> 4;            // 0..31
#pragma unroll
    for (int pass = 0; pass < 2; pass++) {
      int slot = ns + 32 * pass;
      int node = base + slot;
      if (node < N) {
        int d = min(deg[node], SLOT);
        const int* cl = col + node * SLOT;
        float4 acc = *(const float4*)(feat + (size_t)node * D + q * 4);  // self
        int j = 0;
        for (; j + 4 <= d; j += 4) {
          int4 s4 = *(const int4*)(cl + j);
          float4 v0 = *(const float4*)(feat + (size_t)s4.x * D + q * 4);
          float4 v1 = *(const float4*)(feat + (size_t)s4.y * D + q * 4);
          float4 v2 = *(const float4*)(feat + (size_t)s4.z * D + q * 4);
          float4 v3 = *(const float4*)(feat + (size_t)s4.w * D + q * 4);
          acc.x += v0.x + v1.x + v2.x + v3.x;
          acc.y += v0.y + v1.y + v2.y + v3.y;
          acc.z += v0.z + v1.z + v2.z + v3.z;
          acc.w += v0.w + v1.w + v2.w + v3.w;
        }
        for (; j < d; j++) {
          int s = cl[j];
          float4 v = *(const float4*)(feat + (size_t)s * D + q * 4);
          acc.x += v.x; acc.y += v.y; acc.z += v.z; acc.w += v.w;
        }
        if (FOLD_BN) {
          float dp = (float)(d + 1);
          int c = q * 4;
          acc.x = s_bna[c + 0] * acc.x + dp * s_bnb[c + 0];
          acc.y = s_bna[c + 1] * acc.y + dp * s_bnb[c + 1];
          acc.z = s_bna[c + 2] * acc.z + dp * s_bnb[c + 2];
          acc.w = s_bna[c + 3] * acc.w + dp * s_bnb[c + 3];
        }
        *(float4*)&s_in[slot * INP + q * 4] = acc;
      }
    }
  }
  __syncthreads();

  // ---- Phase B: register-tiled MLP ----
  int r2 = tid >> 4;              // 0..31 -> nodes 2r2, 2r2+1
  int n0 = 2 * r2, n1 = n0 + 1;
  int node0 = base + n0, node1 = base + n1;
  constexpr int C1 = MID / 16;    // stage-1 cols per thread (2 or 4)
  float4 o0, o1;
  {
    float acc0[C1], acc1[C1];
#pragma unroll
    for (int u = 0; u < C1; u++) { acc0[u] = ba[q * C1 + u]; acc1[u] = acc0[u]; }
#pragma unroll 4
    for (int j = 0; j < D; j++) {
      float v0 = s_in[n0 * INP + j];
      float v1 = s_in[n1 * INP + j];
#pragma unroll
      for (int u = 0; u < C1; u++) {
        float w = s_Wa[j * MID + q * C1 + u];   // b64/b128, group-broadcast
        acc0[u] += v0 * w;
        acc1[u] += v1 * w;
      }
    }
#pragma unroll
    for (int u = 0; u < C1; u++) {
      acc0[u] = fmaxf(acc0[u], 0.f);
      acc1[u] = fmaxf(acc1[u], 0.f);
    }

    // stage 2: cols 4q..4q+3; mid[k] owner lane = k/C1, reg = k%C1
    o0 = *(const float4*)(bb + q * 4);
    o1 = o0;
#pragma unroll 8
    for (int k = 0; k < MID; k++) {
      float m0 = __shfl(acc0[k % C1], k / C1, 16);
      float m1 = __shfl(acc1[k % C1], k / C1, 16);
      float4 w = *(const float4*)&s_Wb[k * D + q * 4];  // LDS, group-broadcast
      o0.x += m0 * w.x; o0.y += m0 * w.y; o0.z += m0 * w.z; o0.w += m0 * w.w;
      o1.x += m1 * w.x; o1.y += m1 * w.y; o1.z += m1 * w.z; o1.w += m1 * w.w;
    }
    o0.x = fmaxf(o0.x, 0.f); o0.y = fmaxf(o0.y, 0.f);
    o0.z = fmaxf(o0.z, 0.f); o0.w = fmaxf(o0.w, 0.f);
    o1.x = fmaxf(o1.x, 0.f); o1.y = fmaxf(o1.y, 0.f);
    o1.z = fmaxf(o1.z, 0.f); o1.w = fmaxf(o1.w, 0.f);
    if (EPI == 1) {
      if (node0 < N) *(float4*)(out + (size_t)node0 * D + q * 4) = o0;
      if (node1 < N) *(float4*)(out + (size_t)node1 * D + q * 4) = o1;
    }
    if (node0 >= N) o0 = make_float4(0.f, 0.f, 0.f, 0.f);
    if (node1 >= N) o1 = make_float4(0.f, 0.f, 0.f, 0.f);
  }

  if (EPI == 1) {
    // ---- BN-stats epilogue: block tree-reduce sum + sumsq, 128 atomics ----
    __syncthreads();   // all s_in/s_Wb reads done; reuse s_in
    *(float4*)&s_in[r2 * INP + q * 4] =
        make_float4(o0.x + o1.x, o0.y + o1.y, o0.z + o1.z, o0.w + o1.w);
    *(float4*)&s_in[(32 + r2) * INP + q * 4] =
        make_float4(o0.x * o0.x + o1.x * o1.x, o0.y * o0.y + o1.y * o1.y,
                    o0.z * o0.z + o1.z * o1.z, o0.w * o0.w + o1.w * o1.w);
    __syncthreads();
    tree_reduce_2x32(s_in, tid);
    if (tid < D) {
      atomicAdd(&st_sum[tid], s_in[tid]);
      atomicAdd(&st_sq[tid], s_in[32 * INP + tid]);
    }
  }

  if (EPI == 2) {
    // ---- Pool epilogue: per-graph sums (<=2 graphs/block since batch is
    // sorted and graphs are ~6250 nodes), global sumsq, counts ----
    int b0 = (node0 < N) ? batch[node0] : -1;
    int b1 = (node1 < N) ? batch[node1] : -1;
    int g_lo = batch[base];
    int g_hi = batch[min(base + NPB - 1, N - 1)];

    __syncthreads();   // s_in reads done; s_cnt init visible
    // ONLY q==0: the 16 q-lanes of an r2-group share the same two nodes.
    if (q == 0) {
      atomicAdd(&s_cnt[0], (b0 == g_lo ? 1 : 0) + (b1 == g_lo ? 1 : 0));
      if (g_hi != g_lo)
        atomicAdd(&s_cnt[1], (b0 == g_hi ? 1 : 0) + (b1 == g_hi ? 1 : 0));
    }

    // pass A: masked sums for g_lo (rows 0..31) + unmasked squares (32..63)
    float w0 = (b0 == g_lo) ? 1.f : 0.f;
    float w1 = (b1 == g_lo) ? 1.f : 0.f;
    *(float4*)&s_in[r2 * INP + q * 4] =
        make_float4(w0 * o0.x + w1 * o1.x, w0 * o0.y + w1 * o1.y,
                    w0 * o0.z + w1 * o1.z, w0 * o0.w + w1 * o1.w);
    *(float4*)&s_in[(32 + r2) * INP + q * 4] =
        make_float4(o0.x * o0.x + o1.x * o1.x, o0.y * o0.y + o1.y * o1.y,
                    o0.z * o0.z + o1.z * o1.z, o0.w * o0.w + o1.w * o1.w);
    __syncthreads();
    tree_reduce_2x32(s_in, tid);
    if (tid < D) {
      atomicAdd(&st_sum[g_lo * D + tid], s_in[tid]);
      atomicAdd(&st_sq[tid], s_in[32 * INP + tid]);
    }
    if (tid == 0) atomicAdd(&cnt[g_lo], (float)s_cnt[0]);

    if (g_hi != g_lo) {   // block-uniform branch
      __syncthreads();
      float u0 = (b0 == g_hi) ? 1.f : 0.f;
      float u1 = (b1 == g_hi) ? 1.f : 0.f;
      *(float4*)&s_in[r2 * INP + q * 4] =
          make_float4(u0 * o0.x + u1 * o1.x, u0 * o0.y + u1 * o1.y,
                      u0 * o0.z + u1 * o1.z, u0 * o0.w + u1 * o1.w);
      *(float4*)&s_in[(32 + r2) * INP + q * 4] = make_float4(0.f, 0.f, 0.f, 0.f);
      __syncthreads();
      tree_reduce_2x32(s_in, tid);
      if (tid < D) atomicAdd(&st_sum[g_hi * D + tid], s_in[tid]);
      if (tid == 0) atomicAdd(&cnt[g_hi], (float)s_cnt[1]);
    }
  }
}

// ---------------------------------------------------------------------------
// Final: BN2 coeffs from (Σ_g pool, sq) + fused affine + mean divide.
// ---------------------------------------------------------------------------
__global__ void final_kernel(const float* __restrict__ pool,
                             const float* __restrict__ cnt,
                             const float* __restrict__ sq,
                             const float* __restrict__ gamma,
                             const float* __restrict__ beta,
                             float invN, float* __restrict__ out) {
  int c = threadIdx.x;   // 64 threads
  float s = 0.f;
#pragma unroll
  for (int g = 0; g < NG; g++) s += pool[g * D + c];
  float mean = s * invN;
  float var = sq[c] * invN - mean * mean;
  float a = gamma[c] * rsqrtf(var + 1e-5f);
  float b = beta[c] - mean * a;
#pragma unroll
  for (int g = 0; g < NG; g++) {
    float n = cnt[g];
    out[g * D + c] = (a * pool[g * D + c] + n * b) / fmaxf(n, 1.f);
  }
}

extern "C" void kernel_launch(void* const* d_in, const int* in_sizes, int n_in,
                              void* d_out, int out_size, void* d_ws, size_t ws_size,
                              hipStream_t stream) {
  const float* x   = (const float*)d_in[0];
  const int* ei    = (const int*)d_in[1];
  const int* batch = (const int*)d_in[2];
  const float* W1a = (const float*)d_in[5];
  const float* b1a = (const float*)d_in[6];
  const float* W1b = (const float*)d_in[7];
  const float* b1b = (const float*)d_in[8];
  const float* g1  = (const float*)d_in[9];
  const float* be1 = (const float*)d_in[10];
  const float* W2a = (const float*)d_in[11];
  const float* b2a = (const float*)d_in[12];
  const float* W2b = (const float*)d_in[13];
  const float* b2b = (const float*)d_in[14];
  const float* g2  = (const float*)d_in[15];
  const float* be2 = (const float*)d_in[16];

  int N = in_sizes[0] / D;        // 100000
  int E = in_sizes[1] / 2;        // 1600000
  int per = E / NG;               // 100000
  int tmul = N / NG;              // 6250
  float invN = 1.f / (float)N;

  float* ws = (float*)d_ws;
  size_t nd = (size_t)N * D;
  float* h1  = ws;                       // post-MLP1 (pre-BN; BN folded downstream)
  int*   col = (int*)(ws + nd);          // CSR src lists (N*SLOT ints)
  float* stats = ws + 2 * nd;
  float* sum1 = stats;                   // 64
  float* sq1  = stats + 64;              // 64
  float* pool = stats + 128;             // 16*64
  float* cnt  = stats + 128 + NG * D;    // 16
  float* sq2  = stats + 144 + NG * D;    // 64
  int*   fill = (int*)(stats + 208 + NG * D);  // N ints (degree counts)

  // Zero stats + fill (contiguous, ~0.4 MB) in one shot.
  hipMemsetAsync(stats, 0, (208 + NG * D + N) * sizeof(float), stream);

  build_csr_kernel<<<(E + 255) / 256, 256, 0, stream>>>(ei, fill, col, E, per, tmul);

  int fblocks = (N + 63) / 64;

  // Layer 1: gather(x) + MLP1 -> h1 (pre-BN) + BN1-stats epilogue
  fused_layer_kernel<32, false, 1><<<fblocks, 512, 0, stream>>>(
      x, col, fill, nullptr, nullptr, nullptr, nullptr, invN,
      W1a, b1a, W1b, b1b, h1, nullptr, sum1, sq1, nullptr, N);

  // Layer 2: BN1 folded into gather input; pool + sumsq epilogue (no h2!)
  fused_layer_kernel<64, true, 2><<<fblocks, 512, 0, stream>>>(
      h1, col, fill, sum1, sq1, g1, be1, invN,
      W2a, b2a, W2b, b2b, nullptr, batch, pool, sq2, cnt, N);

  // BN2 coeffs + affine + mean.
  final_kernel<<<1, 64, 0, stream>>>(pool, cnt, sq2, g2, be2, invN, (float*)d_out);
}